// Round 1
// baseline (792.430 us; speedup 1.0000x reference)
//
#include <hip/hip_runtime.h>
#include <math.h>

constexpr int N = 2000;
constexpr int C = 256;
constexpr int H = 8;
constexpr int D = 32;
constexpr float SCL = 25.0f;

// ---- ws layout (float offsets) ----
// Qc 0, Kc 512000, Qr 1024000, Kr 1536000, V 2048000, Vn 2560000,
// STATS 3072000 (maxc,sumc,maxr,sumr each [8][2000]),
// SIM 3136000 ([N][N]), XP 7136000 ([16][8][N][32]),
// MASK bytes @ 61312000 ([N][N] u8). Total ~65.3 MB.

// ================= K1: QKV projection + per-head L2 norm =================
__global__ __launch_bounds__(256) void qkv_kernel(
    const float* __restrict__ x, const float* __restrict__ W,
    float* __restrict__ Qo, float* __restrict__ Ko,
    float* __restrict__ Vo, float* __restrict__ Vno, int wantV)
{
    __shared__ float xs[8 * C];
    const int t = threadIdx.x;
    const int n0 = blockIdx.x * 8;
    for (int i = t; i < 8 * C; i += 256) xs[i] = x[n0 * C + i];
    __syncthreads();
    const float4* xs4 = (const float4*)xs;
    const int nw = wantV ? 3 : 2;
    const int h = t >> 5, d = t & 31;
    for (int which = 0; which < nw; ++which) {
        const float4* w4 = (const float4*)(W + (size_t)(which * C + t) * C);
        float acc[8];
        #pragma unroll
        for (int r = 0; r < 8; ++r) acc[r] = 0.f;
        for (int c = 0; c < C / 4; ++c) {
            const float4 wv = w4[c];
            #pragma unroll
            for (int r = 0; r < 8; ++r) {
                const float4 xv = xs4[r * (C / 4) + c];
                acc[r] += wv.x * xv.x + wv.y * xv.y + wv.z * xv.z + wv.w * xv.w;
            }
        }
        #pragma unroll
        for (int r = 0; r < 8; ++r) {
            float ss = acc[r] * acc[r];
            #pragma unroll
            for (int off = 1; off < 32; off <<= 1) ss += __shfl_xor(ss, off);
            const float nv = acc[r] / (sqrtf(ss) + 1e-8f);
            const int n = n0 + r;
            const int idx = (h * N + n) * D + d;
            if (which == 0) Qo[idx] = nv;
            else if (which == 1) Ko[idx] = nv;
            else { Vo[idx] = acc[r]; Vno[idx] = nv; }
        }
    }
}

// ================= K2: per-(h,n) softmax stats (max, sum) =================
__global__ __launch_bounds__(256) void stats_kernel(
    const float* __restrict__ Qc, const float* __restrict__ Kc,
    const float* __restrict__ Qr, const float* __restrict__ Kr,
    const float* __restrict__ clsScore, const float* __restrict__ fgScore,
    float* __restrict__ stats)
{
    const int n0 = blockIdx.x * 32;
    const int h = blockIdx.y;
    const int z = blockIdx.z;
    const float* Q = z ? Qr : Qc;
    const float* K = z ? Kr : Kc;
    const float* score = z ? fgScore : clsScore;
    float* outMax = stats + z * 32000;
    float* outSum = outMax + 16000;

    __shared__ float Qs[32 * 36];
    __shared__ float Ks[64 * 36];
    const int t = threadIdx.x;
    {
        const int f = t * 4, row = f >> 5, col = f & 31;
        float4 v = make_float4(0.f, 0.f, 0.f, 0.f);
        if (n0 + row < N) v = *(const float4*)(Q + (size_t)h * N * D + (size_t)(n0 + row) * D + col);
        *(float4*)&Qs[row * 36 + col] = v;
    }
    const int r = t >> 3, mg = t & 7;
    float M = -1e30f, S = 0.f;
    for (int m0 = 0; m0 < N; m0 += 64) {
        __syncthreads();
        #pragma unroll
        for (int ii = 0; ii < 2; ++ii) {
            const int f = t * 8 + ii * 4, row = f >> 5, col = f & 31;
            float4 v = make_float4(0.f, 0.f, 0.f, 0.f);
            if (m0 + row < N) v = *(const float4*)(K + (size_t)h * N * D + (size_t)(m0 + row) * D + col);
            *(float4*)&Ks[row * 36 + col] = v;
        }
        __syncthreads();
        #pragma unroll
        for (int j = 0; j < 8; ++j) {
            const int ml = mg + 8 * j;
            const int m = m0 + ml;
            if (m >= N) continue;
            const float4* q4 = (const float4*)&Qs[r * 36];
            const float4* k4 = (const float4*)&Ks[ml * 36];
            float dot = 0.f;
            #pragma unroll
            for (int c = 0; c < 8; ++c) {
                const float4 a = q4[c], b = k4[c];
                dot += a.x * b.x + a.y * b.y + a.z * b.z + a.w * b.w;
            }
            const float s = dot * (SCL * score[m]);
            if (s > M) { S = S * __expf(M - s) + 1.f; M = s; }
            else       { S += __expf(s - M); }
        }
    }
    #pragma unroll
    for (int off = 1; off < 8; off <<= 1) {
        const float M2 = __shfl_xor(M, off);
        const float S2 = __shfl_xor(S, off);
        const float Mn = fmaxf(M, M2);
        S = S * __expf(M - Mn) + S2 * __expf(M2 - Mn);
        M = Mn;
    }
    const int n = n0 + r;
    if (mg == 0 && n < N) { outMax[h * N + n] = M; outSum[h * N + n] = S; }
}

// ================= K3: mean-over-h of Vn.Vn^T  ->  u8 mask =================
__global__ __launch_bounds__(256) void vvmask_kernel(
    const float* __restrict__ Vn, unsigned char* __restrict__ Mask)
{
    const int m0 = blockIdx.x * 128;
    const int n0 = blockIdx.y * 16;
    const int t = threadIdx.x;
    __shared__ float An[16 * 36];
    __shared__ float Bt[32 * 132];
    const int ng = t >> 5, mg = t & 31;
    float acc[2][4] = {{0.f,0.f,0.f,0.f},{0.f,0.f,0.f,0.f}};
    for (int h = 0; h < H; ++h) {
        __syncthreads();
        if (t < 128) {
            const int f = t * 4, row = f >> 5, col = f & 31;
            const float4 v = *(const float4*)(Vn + (size_t)h * N * D + (size_t)(n0 + row) * D + col);
            *(float4*)&An[row * 36 + col] = v;
        }
        #pragma unroll
        for (int ii = 0; ii < 4; ++ii) {
            const int f = t * 16 + ii * 4, row = f >> 5, col = f & 31;
            float4 v = make_float4(0.f, 0.f, 0.f, 0.f);
            if (m0 + row < N) v = *(const float4*)(Vn + (size_t)h * N * D + (size_t)(m0 + row) * D + col);
            Bt[(col + 0) * 132 + row] = v.x;
            Bt[(col + 1) * 132 + row] = v.y;
            Bt[(col + 2) * 132 + row] = v.z;
            Bt[(col + 3) * 132 + row] = v.w;
        }
        __syncthreads();
        #pragma unroll
        for (int dd = 0; dd < 32; ++dd) {
            const float a0 = An[(2 * ng) * 36 + dd];
            const float a1 = An[(2 * ng + 1) * 36 + dd];
            const float4 b = *(const float4*)&Bt[dd * 132 + 4 * mg];
            acc[0][0] += a0 * b.x; acc[0][1] += a0 * b.y; acc[0][2] += a0 * b.z; acc[0][3] += a0 * b.w;
            acc[1][0] += a1 * b.x; acc[1][1] += a1 * b.y; acc[1][2] += a1 * b.z; acc[1][3] += a1 * b.w;
        }
    }
    #pragma unroll
    for (int i = 0; i < 2; ++i) {
        const int n = n0 + 2 * ng + i;
        #pragma unroll
        for (int mm = 0; mm < 4; ++mm) {
            const int m = m0 + 4 * mg + mm;
            if (m < N) Mask[(size_t)n * N + m] = (acc[i][mm] * 0.125f > 0.75f) ? (unsigned char)1 : (unsigned char)0;
        }
    }
}

// ================= K4: fused attention (attn = (smx_c+smx_r)*0.5*coord, zero-mask, sim-acc, PV partials) =================
__global__ __launch_bounds__(256) void attn_kernel(
    const float* __restrict__ Qc, const float* __restrict__ Kc,
    const float* __restrict__ Qr, const float* __restrict__ Kr,
    const float* __restrict__ V, const float* __restrict__ coord,
    const float* __restrict__ clsScore, const float* __restrict__ fgScore,
    const float* __restrict__ stats,
    float* __restrict__ SIM, float* __restrict__ XP)
{
    const int m0 = blockIdx.x * 128;
    const int n0 = blockIdx.y * 16;
    const int t = threadIdx.x;

    __shared__ float Qc_s[16 * 36], Qr_s[16 * 36];
    __shared__ float Kc_t[32 * 132], Kr_t[32 * 132];
    __shared__ float V_s[128 * 36];
    __shared__ float attn_s[16 * 132];
    __shared__ float scC[128], scF[128];
    __shared__ float st_s[4][H][16];

    if (t < 128) {
        const int m = m0 + t;
        scC[t] = (m < N) ? clsScore[m] : 0.f;
        scF[t] = (m < N) ? fgScore[m] : 0.f;
    }
    for (int idx = t; idx < 512; idx += 256) {
        const int a = idx >> 7, rem = idx & 127, hh = rem >> 4, rr = rem & 15;
        float v = stats[a * 16000 + hh * N + n0 + rr];
        if (a & 1) v = 1.f / v;
        st_s[a][hh][rr] = v;
    }

    const int ng = t >> 5, mg = t & 31;
    const int tn = t >> 4, td = t & 15;
    float simacc[2][4] = {{0.f,0.f,0.f,0.f},{0.f,0.f,0.f,0.f}};

    for (int h = 0; h < H; ++h) {
        __syncthreads();
        // stage Q tiles (threads 0..127 -> Qc, 128..255 -> Qr)
        {
            const int tt = t & 127;
            const int f = tt * 4, row = f >> 5, col = f & 31;
            const float* src = (t < 128) ? Qc : Qr;
            float* dst = (t < 128) ? Qc_s : Qr_s;
            const float4 v = *(const float4*)(src + (size_t)h * N * D + (size_t)(n0 + row) * D + col);
            *(float4*)&dst[row * 36 + col] = v;
        }
        // stage Kc/Kr transposed + V
        #pragma unroll
        for (int ii = 0; ii < 4; ++ii) {
            const int f = t * 16 + ii * 4, row = f >> 5, col = f & 31;
            const bool ok = (m0 + row < N);
            const size_t gb = (size_t)h * N * D + (size_t)(m0 + row) * D + col;
            float4 vc = make_float4(0.f,0.f,0.f,0.f), vr = vc, vv = vc;
            if (ok) { vc = *(const float4*)(Kc + gb); vr = *(const float4*)(Kr + gb); vv = *(const float4*)(V + gb); }
            Kc_t[(col+0)*132+row] = vc.x; Kc_t[(col+1)*132+row] = vc.y; Kc_t[(col+2)*132+row] = vc.z; Kc_t[(col+3)*132+row] = vc.w;
            Kr_t[(col+0)*132+row] = vr.x; Kr_t[(col+1)*132+row] = vr.y; Kr_t[(col+2)*132+row] = vr.z; Kr_t[(col+3)*132+row] = vr.w;
            *(float4*)&V_s[row * 36 + col] = vv;
        }
        __syncthreads();
        // QK dots: 2 rows x 4 cols per thread
        float accC[2][4] = {{0.f,0.f,0.f,0.f},{0.f,0.f,0.f,0.f}};
        float accR[2][4] = {{0.f,0.f,0.f,0.f},{0.f,0.f,0.f,0.f}};
        #pragma unroll
        for (int dd = 0; dd < 32; ++dd) {
            const float qc0 = Qc_s[(2*ng)*36 + dd];
            const float qc1 = Qc_s[(2*ng+1)*36 + dd];
            const float qr0 = Qr_s[(2*ng)*36 + dd];
            const float qr1 = Qr_s[(2*ng+1)*36 + dd];
            const float4 kc = *(const float4*)&Kc_t[dd*132 + 4*mg];
            const float4 kr = *(const float4*)&Kr_t[dd*132 + 4*mg];
            accC[0][0] += qc0*kc.x; accC[0][1] += qc0*kc.y; accC[0][2] += qc0*kc.z; accC[0][3] += qc0*kc.w;
            accC[1][0] += qc1*kc.x; accC[1][1] += qc1*kc.y; accC[1][2] += qc1*kc.z; accC[1][3] += qc1*kc.w;
            accR[0][0] += qr0*kr.x; accR[0][1] += qr0*kr.y; accR[0][2] += qr0*kr.z; accR[0][3] += qr0*kr.w;
            accR[1][0] += qr1*kr.x; accR[1][1] += qr1*kr.y; accR[1][2] += qr1*kr.z; accR[1][3] += qr1*kr.w;
        }
        // attn values + sim accumulation + attn_s tile
        #pragma unroll
        for (int i = 0; i < 2; ++i) {
            const int nl = 2*ng + i;
            const int n = n0 + nl;
            const float mc = st_s[0][h][nl], ic = st_s[1][h][nl];
            const float mr = st_s[2][h][nl], ir = st_s[3][h][nl];
            const int bs = (n / 10) * 10;
            const float* corow = coord + (size_t)(h * N + n) * N;
            const int mbase = m0 + 4*mg;
            float cov[4] = {0.f,0.f,0.f,0.f};
            if (mbase + 3 < N) {
                const float4 co = *(const float4*)(corow + mbase);
                cov[0]=co.x; cov[1]=co.y; cov[2]=co.z; cov[3]=co.w;
            } else {
                #pragma unroll
                for (int q = 0; q < 4; ++q) if (mbase + q < N) cov[q] = corow[mbase + q];
            }
            float av[4];
            #pragma unroll
            for (int mm = 0; mm < 4; ++mm) {
                const int m = mbase + mm;
                float a = 0.f;
                if (m < N) {
                    const float sc = accC[i][mm] * (SCL * scC[4*mg + mm]);
                    const float sr = accR[i][mm] * (SCL * scF[4*mg + mm]);
                    a = (__expf(sc - mc) * ic + __expf(sr - mr) * ir) * 0.5f * cov[mm];
                    if (m >= bs && m < bs + 9 && m != n) a = 0.f;
                }
                av[mm] = a;
                simacc[i][mm] += a;
            }
            *(float4*)&attn_s[nl * 132 + 4*mg] = make_float4(av[0], av[1], av[2], av[3]);
        }
        __syncthreads();
        // PV partial over this m-tile
        {
            const int d0 = td * 2;
            float a0 = 0.f, a1 = 0.f;
            #pragma unroll 8
            for (int ml = 0; ml < 128; ++ml) {
                const float a = attn_s[tn * 132 + ml];
                const float2 vv = *(const float2*)&V_s[ml * 36 + d0];
                a0 += a * vv.x; a1 += a * vv.y;
            }
            const int n = n0 + tn;
            const size_t off = ((size_t)(blockIdx.x * H + h) * N + n) * D + d0;
            *(float2*)&XP[off] = make_float2(a0, a1);
        }
    }
    // SIM writes (mean over heads)
    #pragma unroll
    for (int i = 0; i < 2; ++i) {
        const int n = n0 + 2*ng + i;
        const int mbase = m0 + 4*mg;
        if (mbase + 3 < N) {
            *(float4*)&SIM[(size_t)n * N + mbase] =
                make_float4(simacc[i][0]*0.125f, simacc[i][1]*0.125f, simacc[i][2]*0.125f, simacc[i][3]*0.125f);
        } else {
            #pragma unroll
            for (int q = 0; q < 4; ++q)
                if (mbase + q < N) SIM[(size_t)n * N + mbase + q] = simacc[i][q]*0.125f;
        }
    }
}

// ================= K5: reduce PV partials -> x_cat =================
__global__ __launch_bounds__(256) void reduce_kernel(
    const float* __restrict__ XP, const float* __restrict__ V, float* __restrict__ out)
{
    const int n = blockIdx.x;
    const int t = threadIdx.x;
    const int h = t >> 5, d = t & 31;
    float acc = 0.f;
    #pragma unroll
    for (int mt = 0; mt < 16; ++mt)
        acc += XP[((size_t)(mt * H + h) * N + n) * D + d];
    out[(size_t)n * 512 + t] = acc;
    out[(size_t)n * 512 + 256 + t] = V[(size_t)(h * N + n) * D + d];
}

// ================= K6: row softmax of SIM + masked renorm =================
__global__ __launch_bounds__(256) void simfinal_kernel(
    const float* __restrict__ SIM, const unsigned char* __restrict__ Mask,
    float* __restrict__ out)
{
    __shared__ float buf[N];
    __shared__ float redA[4], redB[4];
    const int n = blockIdx.x, t = threadIdx.x;
    const float* row = SIM + (size_t)n * N;
    const unsigned char* mrow = Mask + (size_t)n * N;
    float mx = -1e30f;
    for (int i = t; i < N; i += 256) { const float v = row[i]; buf[i] = v; mx = fmaxf(mx, v); }
    #pragma unroll
    for (int off = 1; off < 64; off <<= 1) mx = fmaxf(mx, __shfl_xor(mx, off));
    const int wv = t >> 6;
    if ((t & 63) == 0) redA[wv] = mx;
    __syncthreads();
    const float M = fmaxf(fmaxf(redA[0], redA[1]), fmaxf(redA[2], redA[3]));
    float sA = 0.f, sM = 0.f;
    for (int i = t; i < N; i += 256) {
        const float e = __expf(buf[i] - M);
        buf[i] = e;
        sA += e;
        sM += mrow[i] ? e : 0.f;
    }
    #pragma unroll
    for (int off = 1; off < 64; off <<= 1) { sA += __shfl_xor(sA, off); sM += __shfl_xor(sM, off); }
    __syncthreads();
    if ((t & 63) == 0) { redA[wv] = sA; redB[wv] = sM; }
    __syncthreads();
    const float SA = redA[0] + redA[1] + redA[2] + redA[3];
    const float SMK = redB[0] + redB[1] + redB[2] + redB[3];
    const float inv = 1.f / (SMK + 1e-8f * SA);
    float* orow = out + 1024000 + (size_t)n * N;
    for (int i = t; i < N; i += 256) orow[i] = mrow[i] ? buf[i] * inv : 0.f;
}

extern "C" void kernel_launch(void* const* d_in, const int* in_sizes, int n_in,
                              void* d_out, int out_size, void* d_ws, size_t ws_size,
                              hipStream_t stream) {
    const float* x_cls     = (const float*)d_in[0];
    const float* x_reg     = (const float*)d_in[1];
    const float* cls_score = (const float*)d_in[2];
    const float* fg_score  = (const float*)d_in[3];
    const float* coord     = (const float*)d_in[4];
    const float* Wc        = (const float*)d_in[5];
    const float* Wr        = (const float*)d_in[6];

    float* ws = (float*)d_ws;
    float* Qc  = ws + 0;
    float* Kc  = ws + 512000;
    float* Qr  = ws + 1024000;
    float* Kr  = ws + 1536000;
    float* V   = ws + 2048000;
    float* Vn  = ws + 2560000;
    float* ST  = ws + 3072000;
    float* SIM = ws + 3136000;
    float* XP  = ws + 7136000;
    unsigned char* Mask = (unsigned char*)d_ws + 61312000ull;
    float* out = (float*)d_out;

    qkv_kernel<<<250, 256, 0, stream>>>(x_cls, Wc, Qc, Kc, V, Vn, 1);
    qkv_kernel<<<250, 256, 0, stream>>>(x_reg, Wr, Qr, Kr, nullptr, nullptr, 0);
    stats_kernel<<<dim3(63, 8, 2), 256, 0, stream>>>(Qc, Kc, Qr, Kr, cls_score, fg_score, ST);
    vvmask_kernel<<<dim3(16, 125), 256, 0, stream>>>(Vn, Mask);
    attn_kernel<<<dim3(16, 125), 256, 0, stream>>>(Qc, Kc, Qr, Kr, V, coord, cls_score, fg_score, ST, SIM, XP);
    reduce_kernel<<<2000, 256, 0, stream>>>(XP, V, out);
    simfinal_kernel<<<2000, 256, 0, stream>>>(SIM, Mask, out);
}

// Round 2
// 379.962 us; speedup vs baseline: 2.0856x; 2.0856x over previous
//
#include <hip/hip_runtime.h>
#include <math.h>

typedef _Float16 half8 __attribute__((ext_vector_type(8)));
typedef float f32x4 __attribute__((ext_vector_type(4)));

constexpr int N = 2000;
constexpr int NP = 2048;   // padded row count for f16 tensors
constexpr int H = 8;
constexpr int D = 32;
constexpr float SCL = 25.0f;

#define MFMA16(a,b,c) __builtin_amdgcn_mfma_f32_16x16x32_f16((a),(b),(c),0,0,0)

// ---- ws layout (float offsets) ----
// V f32 [8][2000][32]            @ 0         (512000)
// ST   [2z][2kind][8][2048]      @ 512000    (65536)   kind0=max kind1=sum
// SIM  [2000][2000]              @ 577536    (4000000)
// XP   [8mc][8h][2000][32]       @ 4577536   (4096000)
// f16 @ float-offset 8673536: Qch,Kch,Qrh,Krh,Vnh  [8][2048][32]; Vth [8][32][2048]
// Mask u8 [2000][2000] after.  Total ~45 MB.

// ================= K1: QKV projection + L2 norm, f16 emission =================
__global__ __launch_bounds__(256) void qkv_kernel(
    const float* __restrict__ x, const float* __restrict__ W,
    _Float16* __restrict__ Qh, _Float16* __restrict__ Kh,
    float* __restrict__ V, _Float16* __restrict__ Vnh, _Float16* __restrict__ Vth,
    int wantV)
{
    const int t = threadIdx.x;
    const int n0 = blockIdx.x * 8;
    const int h = t >> 5, d = t & 31;
    if (n0 >= N) {  // zero-fill pad rows 2000..2047
        for (int r = 0; r < 8; ++r) {
            const int n = n0 + r;
            Qh[(h*NP + n)*D + d] = (_Float16)0.f;
            Kh[(h*NP + n)*D + d] = (_Float16)0.f;
            if (wantV) { Vnh[(h*NP + n)*D + d] = (_Float16)0.f; Vth[((size_t)(h*D + d))*NP + n] = (_Float16)0.f; }
        }
        return;
    }
    __shared__ float xs[8 * 256];
    for (int i = t; i < 8 * 256; i += 256) xs[i] = x[n0 * 256 + i];
    __syncthreads();
    const float4* xs4 = (const float4*)xs;
    const int nw = wantV ? 3 : 2;
    for (int which = 0; which < nw; ++which) {
        const float4* w4 = (const float4*)(W + (size_t)(which * 256 + t) * 256);
        float acc[8];
        #pragma unroll
        for (int r = 0; r < 8; ++r) acc[r] = 0.f;
        for (int c = 0; c < 64; ++c) {
            const float4 wv = w4[c];
            #pragma unroll
            for (int r = 0; r < 8; ++r) {
                const float4 xv = xs4[r * 64 + c];
                acc[r] += wv.x * xv.x + wv.y * xv.y + wv.z * xv.z + wv.w * xv.w;
            }
        }
        #pragma unroll
        for (int r = 0; r < 8; ++r) {
            float ss = acc[r] * acc[r];
            #pragma unroll
            for (int off = 1; off < 32; off <<= 1) ss += __shfl_xor(ss, off);
            const float nv = acc[r] / (sqrtf(ss) + 1e-8f);
            const int n = n0 + r;
            if (which == 0)      Qh[(h*NP + n)*D + d] = (_Float16)nv;
            else if (which == 1) Kh[(h*NP + n)*D + d] = (_Float16)nv;
            else { V[((size_t)h*N + n)*D + d] = acc[r]; Vnh[(h*NP + n)*D + d] = (_Float16)nv; }
        }
        if (which == 2) {
            half8 vv;
            #pragma unroll
            for (int r = 0; r < 8; ++r) vv[r] = (_Float16)acc[r];
            *(half8*)(Vth + ((size_t)(h*D + d))*NP + n0) = vv;  // transposed V, 16B store
        }
    }
}

// ================= K2: softmax stats via MFMA =================
__global__ __launch_bounds__(256) void stats_kernel(
    const _Float16* __restrict__ Qch, const _Float16* __restrict__ Kch,
    const _Float16* __restrict__ Qrh, const _Float16* __restrict__ Krh,
    const float* __restrict__ clsScore, const float* __restrict__ fgScore,
    float* __restrict__ ST)
{
    const int t = threadIdx.x;
    const int w = t >> 6, l = t & 63;
    const int n0 = blockIdx.x * 64 + w * 16;
    if (n0 >= N) return;
    const int h = blockIdx.y, z = blockIdx.z;
    const _Float16* Q = z ? Qrh : Qch;
    const _Float16* K = z ? Krh : Kch;
    const float* score = z ? fgScore : clsScore;
    const int lr = l & 15, lg = l >> 4;
    const half8 aQ = *(const half8*)(Q + ((size_t)(h*NP + n0 + lr))*D + lg*8);
    float M[4], S[4];
    #pragma unroll
    for (int j = 0; j < 4; ++j) { M[j] = -1e30f; S[j] = 0.f; }
    for (int ms = 0; ms < 125; ++ms) {
        const int m = ms*16 + lr;
        const half8 bK = *(const half8*)(K + ((size_t)(h*NP + m))*D + lg*8);
        f32x4 z4 = {0.f, 0.f, 0.f, 0.f};
        const f32x4 c = MFMA16(aQ, bK, z4);
        const float sm = SCL * score[m];
        #pragma unroll
        for (int j = 0; j < 4; ++j) {
            const float s = c[j] * sm;
            if (s > M[j]) { S[j] = S[j]*__expf(M[j]-s) + 1.f; M[j] = s; }
            else          { S[j] += __expf(s - M[j]); }
        }
    }
    #pragma unroll
    for (int j = 0; j < 4; ++j) {
        #pragma unroll
        for (int off = 1; off < 16; off <<= 1) {
            const float M2 = __shfl_xor(M[j], off);
            const float S2 = __shfl_xor(S[j], off);
            const float Mn = fmaxf(M[j], M2);
            S[j] = S[j]*__expf(M[j]-Mn) + S2*__expf(M2-Mn);
            M[j] = Mn;
        }
        if (lr == 0) {
            const int n = n0 + lg*4 + j;
            ST[((size_t)(z*2 + 0)*H + h)*NP + n] = M[j];
            ST[((size_t)(z*2 + 1)*H + h)*NP + n] = S[j];
        }
    }
}

// ================= K3: mean-over-h of Vn.Vn^T -> u8 mask (MFMA) =================
__global__ __launch_bounds__(256) void vvmask_kernel(
    const _Float16* __restrict__ Vnh, unsigned char* __restrict__ Mask)
{
    const int t = threadIdx.x;
    const int w = t >> 6, l = t & 63;
    const int n0 = blockIdx.y * 16;
    const int m00 = blockIdx.x * 256 + w * 64;
    const int lr = l & 15, lg = l >> 4;
    half8 aV[8];
    #pragma unroll
    for (int h = 0; h < 8; ++h)
        aV[h] = *(const half8*)(Vnh + ((size_t)(h*NP + n0 + lr))*D + lg*8);
    for (int s = 0; s < 4; ++s) {
        const int mb = m00 + s*16;
        f32x4 acc = {0.f, 0.f, 0.f, 0.f};
        #pragma unroll
        for (int h = 0; h < 8; ++h) {
            const half8 bV = *(const half8*)(Vnh + ((size_t)(h*NP + mb + lr))*D + lg*8);
            acc = MFMA16(aV[h], bV, acc);
        }
        const int m = mb + lr;
        if (m < N) {
            #pragma unroll
            for (int j = 0; j < 4; ++j) {
                const int n = n0 + lg*4 + j;
                Mask[(size_t)n*N + m] = (acc[j]*0.125f > 0.75f) ? (unsigned char)1 : (unsigned char)0;
            }
        }
    }
}

// ================= K4: fused attention (MFMA QK + PV, LDS SIM accum) =================
__global__ __launch_bounds__(256) void attn_kernel(
    const _Float16* __restrict__ Qch, const _Float16* __restrict__ Kch,
    const _Float16* __restrict__ Qrh, const _Float16* __restrict__ Krh,
    const _Float16* __restrict__ Vth, const float* __restrict__ coord,
    const float* __restrict__ clsScore, const float* __restrict__ fgScore,
    const float* __restrict__ ST,
    float* __restrict__ SIM, float* __restrict__ XP)
{
    constexpr int AP = 264;  // att_s f16 col stride
    constexpr int SP = 257;  // SIM_s f32 col stride
    __shared__ float SIM_s[16 * SP];
    __shared__ _Float16 att_s[4][16 * AP];
    __shared__ float st_s[4][H][16];

    const int t = threadIdx.x;
    const int w = t >> 6, l = t & 63;
    const int mc = blockIdx.x;
    const int m0 = mc * 256;
    const int n0 = blockIdx.y * 16;
    const int lr = l & 15, lg = l >> 4;

    for (int i = t; i < 16 * SP; i += 256) SIM_s[i] = 0.f;
    for (int i = t; i < 4 * H * 16; i += 256) {
        const int a = i >> 7, h = (i >> 4) & 7, r = i & 15;
        float v = ST[((size_t)a*H + h)*NP + n0 + r];
        if (a & 1) v = 1.f / v;
        st_s[a][h][r] = v;
    }
    __syncthreads();

    int nj[4], bsj[4];
    #pragma unroll
    for (int j = 0; j < 4; ++j) { nj[j] = n0 + lg*4 + j; bsj[j] = (nj[j]/10)*10; }

    for (int hp = 0; hp < 2; ++hp) {
        const int h = w + hp*4;
        const half8 aQc = *(const half8*)(Qch + ((size_t)(h*NP + n0 + lr))*D + lg*8);
        const half8 aQr = *(const half8*)(Qrh + ((size_t)(h*NP + n0 + lr))*D + lg*8);
        float mC[4], iC[4], mR[4], iR[4];
        #pragma unroll
        for (int j = 0; j < 4; ++j) {
            const int r = lg*4 + j;
            mC[j] = st_s[0][h][r]; iC[j] = st_s[1][h][r];
            mR[j] = st_s[2][h][r]; iR[j] = st_s[3][h][r];
        }
        for (int ms = 0; ms < 16; ++ms) {
            const int col = ms*16 + lr;
            const int m = m0 + col;
            const half8 bKc = *(const half8*)(Kch + ((size_t)(h*NP + m))*D + lg*8);
            const half8 bKr = *(const half8*)(Krh + ((size_t)(h*NP + m))*D + lg*8);
            f32x4 z4 = {0.f, 0.f, 0.f, 0.f};
            const f32x4 cc = MFMA16(aQc, bKc, z4);
            const f32x4 cr = MFMA16(aQr, bKr, z4);
            if (m < N) {
                const float sCm = SCL * clsScore[m];
                const float sFm = SCL * fgScore[m];
                #pragma unroll
                for (int j = 0; j < 4; ++j) {
                    const float eC = __expf(cc[j]*sCm - mC[j]) * iC[j];
                    const float eR = __expf(cr[j]*sFm - mR[j]) * iR[j];
                    const float co = coord[((size_t)h*N + nj[j])*N + m];
                    float a = (eC + eR) * 0.5f * co;
                    if (m >= bsj[j] && m < bsj[j]+9 && m != nj[j]) a = 0.f;
                    att_s[w][(lg*4+j)*AP + col] = (_Float16)a;
                    atomicAdd(&SIM_s[(lg*4+j)*SP + col], a);
                }
            } else {
                #pragma unroll
                for (int j = 0; j < 4; ++j)
                    att_s[w][(lg*4+j)*AP + col] = (_Float16)0.f;
            }
        }
        // PV for this head: attn [16n x 256m] @ V [256m x 32d]
        f32x4 pv0 = {0.f,0.f,0.f,0.f}, pv1 = {0.f,0.f,0.f,0.f};
        #pragma unroll
        for (int kc = 0; kc < 8; ++kc) {
            const half8 aA  = *(const half8*)&att_s[w][lr*AP + kc*32 + lg*8];
            const half8 bV0 = *(const half8*)(Vth + ((size_t)(h*D + lr))*NP + m0 + kc*32 + lg*8);
            const half8 bV1 = *(const half8*)(Vth + ((size_t)(h*D + 16 + lr))*NP + m0 + kc*32 + lg*8);
            pv0 = MFMA16(aA, bV0, pv0);
            pv1 = MFMA16(aA, bV1, pv1);
        }
        #pragma unroll
        for (int j = 0; j < 4; ++j) {
            const int n = nj[j];
            XP[((size_t)(mc*H + h)*N + n)*D + lr]      = pv0[j];
            XP[((size_t)(mc*H + h)*N + n)*D + 16 + lr] = pv1[j];
        }
    }
    __syncthreads();
    for (int i = t; i < 16 * 256; i += 256) {
        const int row = i >> 8, col = i & 255;
        if (m0 + col < N)
            SIM[(size_t)(n0 + row)*N + m0 + col] = SIM_s[row*SP + col] * 0.125f;
    }
}

// ================= K5: reduce PV partials -> x_cat =================
__global__ __launch_bounds__(256) void reduce_kernel(
    const float* __restrict__ XP, const float* __restrict__ V, float* __restrict__ out)
{
    const int n = blockIdx.x, t = threadIdx.x;
    const int h = t >> 5, d = t & 31;
    float acc = 0.f;
    #pragma unroll
    for (int mcI = 0; mcI < 8; ++mcI)
        acc += XP[((size_t)(mcI*H + h)*N + n)*D + d];
    out[(size_t)n*512 + t] = acc;
    out[(size_t)n*512 + 256 + t] = V[((size_t)h*N + n)*D + d];
}

// ================= K6: row softmax of SIM + masked renorm =================
__global__ __launch_bounds__(256) void simfinal_kernel(
    const float* __restrict__ SIM, const unsigned char* __restrict__ Mask,
    float* __restrict__ out)
{
    __shared__ float buf[N];
    __shared__ float redA[4], redB[4];
    const int n = blockIdx.x, t = threadIdx.x;
    const float* row = SIM + (size_t)n * N;
    const unsigned char* mrow = Mask + (size_t)n * N;
    float mx = -1e30f;
    for (int i = t; i < N; i += 256) { const float v = row[i]; buf[i] = v; mx = fmaxf(mx, v); }
    #pragma unroll
    for (int off = 1; off < 64; off <<= 1) mx = fmaxf(mx, __shfl_xor(mx, off));
    const int wv = t >> 6;
    if ((t & 63) == 0) redA[wv] = mx;
    __syncthreads();
    const float M = fmaxf(fmaxf(redA[0], redA[1]), fmaxf(redA[2], redA[3]));
    float sA = 0.f, sM = 0.f;
    for (int i = t; i < N; i += 256) {
        const float e = __expf(buf[i] - M);
        buf[i] = e;
        sA += e;
        sM += mrow[i] ? e : 0.f;
    }
    #pragma unroll
    for (int off = 1; off < 64; off <<= 1) { sA += __shfl_xor(sA, off); sM += __shfl_xor(sM, off); }
    __syncthreads();
    if ((t & 63) == 0) { redA[wv] = sA; redB[wv] = sM; }
    __syncthreads();
    const float SA = redA[0] + redA[1] + redA[2] + redA[3];
    const float SMK = redB[0] + redB[1] + redB[2] + redB[3];
    const float inv = 1.f / (SMK + 1e-8f * SA);
    float* orow = out + 1024000 + (size_t)n * N;
    for (int i = t; i < N; i += 256) orow[i] = mrow[i] ? buf[i] * inv : 0.f;
}

extern "C" void kernel_launch(void* const* d_in, const int* in_sizes, int n_in,
                              void* d_out, int out_size, void* d_ws, size_t ws_size,
                              hipStream_t stream) {
    const float* x_cls     = (const float*)d_in[0];
    const float* x_reg     = (const float*)d_in[1];
    const float* cls_score = (const float*)d_in[2];
    const float* fg_score  = (const float*)d_in[3];
    const float* coord     = (const float*)d_in[4];
    const float* Wc        = (const float*)d_in[5];
    const float* Wr        = (const float*)d_in[6];

    float* ws = (float*)d_ws;
    float* V   = ws;
    float* ST  = ws + 512000;
    float* SIM = ws + 577536;
    float* XP  = ws + 4577536;
    _Float16* F16 = (_Float16*)(ws + 8673536);
    _Float16* Qch = F16;
    _Float16* Kch = F16 + 524288;
    _Float16* Qrh = F16 + 2*524288;
    _Float16* Krh = F16 + 3*524288;
    _Float16* Vnh = F16 + 4*524288;
    _Float16* Vth = F16 + 5*524288;
    unsigned char* Mask = (unsigned char*)(F16 + 6*524288);
    float* out = (float*)d_out;

    qkv_kernel<<<256, 256, 0, stream>>>(x_cls, Wc, Qch, Kch, V, Vnh, Vth, 1);
    qkv_kernel<<<256, 256, 0, stream>>>(x_reg, Wr, Qrh, Krh, nullptr, nullptr, nullptr, 0);
    stats_kernel<<<dim3(32, 8, 2), 256, 0, stream>>>(Qch, Kch, Qrh, Krh, cls_score, fg_score, ST);
    vvmask_kernel<<<dim3(8, 125), 256, 0, stream>>>(Vnh, Mask);
    attn_kernel<<<dim3(8, 125), 256, 0, stream>>>(Qch, Kch, Qrh, Krh, Vth, coord, cls_score, fg_score, ST, SIM, XP);
    reduce_kernel<<<2000, 256, 0, stream>>>(XP, V, out);
    simfinal_kernel<<<2000, 256, 0, stream>>>(SIM, Mask, out);
}

// Round 3
// 204.327 us; speedup vs baseline: 3.8782x; 1.8596x over previous
//
#include <hip/hip_runtime.h>
#include <math.h>

typedef _Float16 half8 __attribute__((ext_vector_type(8)));
typedef float f32x4 __attribute__((ext_vector_type(4)));

constexpr int N = 2000;
constexpr int NP = 2048;   // padded row count for f16 tensors
constexpr int H = 8;
constexpr int D = 32;
constexpr float SCL = 25.0f;

#define MFMA16(a,b,c) __builtin_amdgcn_mfma_f32_16x16x32_f16((a),(b),(c),0,0,0)

// ---- ws layout (float offsets) ----
// V f32 [8][2000][32]            @ 0         (512000)
// ST   [2z][2kind][8][2048]      @ 512000    (65536)
// SIM  [2000][2000]              @ 577536    (4000000)
// XP   [8mc][8h][2000][32]       @ 4577536   (4096000)
// f16 @ float-offset 8673536: Qch,Kch,Qrh,Krh,Vnh  [8][2048][32]; Vth [8][32][2048]
// Mask u8 [2000][2000] after.

// ================= K1: QKV projection + L2 norm, f16 emission (which = blockIdx.y) =================
__global__ __launch_bounds__(256) void qkv_kernel(
    const float* __restrict__ x, const float* __restrict__ W,
    _Float16* __restrict__ Qh, _Float16* __restrict__ Kh,
    float* __restrict__ V, _Float16* __restrict__ Vnh, _Float16* __restrict__ Vth)
{
    const int t = threadIdx.x;
    const int n0 = blockIdx.x * 8;
    const int which = blockIdx.y;
    const int h = t >> 5, d = t & 31;
    if (n0 >= N) {  // zero-fill pad rows 2000..2047
        for (int r = 0; r < 8; ++r) {
            const int n = n0 + r;
            if (which == 0) Qh[(h*NP + n)*D + d] = (_Float16)0.f;
            else if (which == 1) Kh[(h*NP + n)*D + d] = (_Float16)0.f;
            else { Vnh[(h*NP + n)*D + d] = (_Float16)0.f; Vth[((size_t)(h*D + d))*NP + n] = (_Float16)0.f; }
        }
        return;
    }
    __shared__ float xs[8 * 256];
    for (int i = t; i < 8 * 256; i += 256) xs[i] = x[n0 * 256 + i];
    __syncthreads();
    const float4* xs4 = (const float4*)xs;
    const float4* w4 = (const float4*)(W + (size_t)(which * 256 + t) * 256);
    float acc[8];
    #pragma unroll
    for (int r = 0; r < 8; ++r) acc[r] = 0.f;
    for (int c = 0; c < 64; ++c) {
        const float4 wv = w4[c];
        #pragma unroll
        for (int r = 0; r < 8; ++r) {
            const float4 xv = xs4[r * 64 + c];
            acc[r] += wv.x * xv.x + wv.y * xv.y + wv.z * xv.z + wv.w * xv.w;
        }
    }
    #pragma unroll
    for (int r = 0; r < 8; ++r) {
        float ss = acc[r] * acc[r];
        #pragma unroll
        for (int off = 1; off < 32; off <<= 1) ss += __shfl_xor(ss, off);
        const float nv = acc[r] / (sqrtf(ss) + 1e-8f);
        const int n = n0 + r;
        if (which == 0)      Qh[(h*NP + n)*D + d] = (_Float16)nv;
        else if (which == 1) Kh[(h*NP + n)*D + d] = (_Float16)nv;
        else { V[((size_t)h*N + n)*D + d] = acc[r]; Vnh[(h*NP + n)*D + d] = (_Float16)nv; }
    }
    if (which == 2) {
        half8 vv;
        #pragma unroll
        for (int r = 0; r < 8; ++r) vv[r] = (_Float16)acc[r];
        *(half8*)(Vth + ((size_t)(h*D + d))*NP + n0) = vv;
    }
}

// ================= K2: softmax stats via MFMA =================
__global__ __launch_bounds__(256) void stats_kernel(
    const _Float16* __restrict__ Qch, const _Float16* __restrict__ Kch,
    const _Float16* __restrict__ Qrh, const _Float16* __restrict__ Krh,
    const float* __restrict__ clsScore, const float* __restrict__ fgScore,
    float* __restrict__ ST)
{
    const int t = threadIdx.x;
    const int w = t >> 6, l = t & 63;
    const int n0 = blockIdx.x * 64 + w * 16;
    if (n0 >= N) return;
    const int h = blockIdx.y, z = blockIdx.z;
    const _Float16* Q = z ? Qrh : Qch;
    const _Float16* K = z ? Krh : Kch;
    const float* score = z ? fgScore : clsScore;
    const int lr = l & 15, lg = l >> 4;
    const half8 aQ = *(const half8*)(Q + ((size_t)(h*NP + n0 + lr))*D + lg*8);
    float M[4], S[4];
    #pragma unroll
    for (int j = 0; j < 4; ++j) { M[j] = -1e30f; S[j] = 0.f; }
    for (int ms = 0; ms < 125; ++ms) {
        const int m = ms*16 + lr;
        const half8 bK = *(const half8*)(K + ((size_t)(h*NP + m))*D + lg*8);
        f32x4 z4 = {0.f, 0.f, 0.f, 0.f};
        const f32x4 c = MFMA16(aQ, bK, z4);
        const float sm = SCL * score[m];
        #pragma unroll
        for (int j = 0; j < 4; ++j) {
            const float s = c[j] * sm;
            if (s > M[j]) { S[j] = S[j]*__expf(M[j]-s) + 1.f; M[j] = s; }
            else          { S[j] += __expf(s - M[j]); }
        }
    }
    #pragma unroll
    for (int j = 0; j < 4; ++j) {
        #pragma unroll
        for (int off = 1; off < 16; off <<= 1) {
            const float M2 = __shfl_xor(M[j], off);
            const float S2 = __shfl_xor(S[j], off);
            const float Mn = fmaxf(M[j], M2);
            S[j] = S[j]*__expf(M[j]-Mn) + S2*__expf(M2-Mn);
            M[j] = Mn;
        }
        if (lr == 0) {
            const int n = n0 + lg*4 + j;
            ST[((size_t)(z*2 + 0)*H + h)*NP + n] = M[j];
            ST[((size_t)(z*2 + 1)*H + h)*NP + n] = S[j];
        }
    }
}

// ================= K3: mean-over-h of Vn.Vn^T -> u8 mask (MFMA) =================
__global__ __launch_bounds__(256) void vvmask_kernel(
    const _Float16* __restrict__ Vnh, unsigned char* __restrict__ Mask)
{
    const int t = threadIdx.x;
    const int w = t >> 6, l = t & 63;
    const int n0 = blockIdx.y * 16;
    const int m00 = blockIdx.x * 256 + w * 64;
    const int lr = l & 15, lg = l >> 4;
    half8 aV[8];
    #pragma unroll
    for (int h = 0; h < 8; ++h)
        aV[h] = *(const half8*)(Vnh + ((size_t)(h*NP + n0 + lr))*D + lg*8);
    for (int s = 0; s < 4; ++s) {
        const int mb = m00 + s*16;
        f32x4 acc = {0.f, 0.f, 0.f, 0.f};
        #pragma unroll
        for (int h = 0; h < 8; ++h) {
            const half8 bV = *(const half8*)(Vnh + ((size_t)(h*NP + mb + lr))*D + lg*8);
            acc = MFMA16(aV[h], bV, acc);
        }
        const int m = mb + lr;
        if (m < N) {
            #pragma unroll
            for (int j = 0; j < 4; ++j) {
                const int n = n0 + lg*4 + j;
                Mask[(size_t)n*N + m] = (acc[j]*0.125f > 0.75f) ? (unsigned char)1 : (unsigned char)0;
            }
        }
    }
}

// ================= K4: fused attention — wave owns 64-col m-slice, loops all heads =================
__global__ __launch_bounds__(256) void attn_kernel(
    const _Float16* __restrict__ Qch, const _Float16* __restrict__ Kch,
    const _Float16* __restrict__ Qrh, const _Float16* __restrict__ Krh,
    const _Float16* __restrict__ Vth, const float* __restrict__ coord,
    const float* __restrict__ clsScore, const float* __restrict__ fgScore,
    const float* __restrict__ ST,
    float* __restrict__ SIM, float* __restrict__ XP)
{
    constexpr int AP = 264;  // att_s f16 col stride
    __shared__ _Float16 att_s[16 * AP];        // one head's 16x256 attn tile (f16)
    __shared__ float pvred[4][2][16][17];      // per-wave PV partials, padded
    __shared__ float st_s[4][H][16];

    const int t = threadIdx.x;
    const int w = t >> 6, l = t & 63;
    const int mc = blockIdx.x;
    const int m0 = mc * 256;
    const int n0 = blockIdx.y * 16;
    const int lr = l & 15, lg = l >> 4;
    const int colbase = w * 64;

    for (int i = t; i < 4 * H * 16; i += 256) {
        const int a = i >> 7, h = (i >> 4) & 7, r = i & 15;
        float v = ST[((size_t)a*H + h)*NP + n0 + r];
        if (a & 1) v = 1.f / v;
        st_s[a][h][r] = v;
    }

    // per-lane column info (fixed across heads)
    int mI[4]; bool mOk[4]; float sC[4], sF[4];
    #pragma unroll
    for (int s = 0; s < 4; ++s) {
        mI[s] = m0 + colbase + s*16 + lr;
        mOk[s] = mI[s] < N;
        sC[s] = mOk[s] ? SCL * clsScore[mI[s]] : 0.f;
        sF[s] = mOk[s] ? SCL * fgScore[mI[s]] : 0.f;
    }
    int nj[4], bsj[4];
    #pragma unroll
    for (int j = 0; j < 4; ++j) { nj[j] = n0 + lg*4 + j; bsj[j] = (nj[j]/10)*10; }

    float simacc[4][4];
    #pragma unroll
    for (int s = 0; s < 4; ++s)
        #pragma unroll
        for (int j = 0; j < 4; ++j) simacc[s][j] = 0.f;

    __syncthreads();

    for (int h = 0; h < H; ++h) {
        // prefetch coord (16 independent scalar loads; L3-resident stream)
        float co[4][4];
        #pragma unroll
        for (int s = 0; s < 4; ++s)
            #pragma unroll
            for (int j = 0; j < 4; ++j)
                co[s][j] = mOk[s] ? coord[((size_t)h*N + nj[j])*N + mI[s]] : 0.f;

        const half8 aQc = *(const half8*)(Qch + ((size_t)(h*NP + n0 + lr))*D + lg*8);
        const half8 aQr = *(const half8*)(Qrh + ((size_t)(h*NP + n0 + lr))*D + lg*8);
        float mC[4], iC[4], mR[4], iR[4];
        #pragma unroll
        for (int j = 0; j < 4; ++j) {
            const int r = lg*4 + j;
            mC[j] = st_s[0][h][r]; iC[j] = st_s[1][h][r];
            mR[j] = st_s[2][h][r]; iR[j] = st_s[3][h][r];
        }
        // QK + attn for this wave's 4 col-subtiles
        #pragma unroll
        for (int s = 0; s < 4; ++s) {
            const int mb = m0 + colbase + s*16;
            const half8 bKc = *(const half8*)(Kch + ((size_t)(h*NP + mb + lr))*D + lg*8);
            const half8 bKr = *(const half8*)(Krh + ((size_t)(h*NP + mb + lr))*D + lg*8);
            f32x4 z4 = {0.f, 0.f, 0.f, 0.f};
            const f32x4 cc = MFMA16(aQc, bKc, z4);
            const f32x4 cr = MFMA16(aQr, bKr, z4);
            #pragma unroll
            for (int j = 0; j < 4; ++j) {
                float a = 0.f;
                if (mOk[s]) {
                    const float eC = __expf(cc[j]*sC[s] - mC[j]) * iC[j];
                    const float eR = __expf(cr[j]*sF[s] - mR[j]) * iR[j];
                    a = (eC + eR) * 0.5f * co[s][j];
                    const int m = mI[s];
                    if (m >= bsj[j] && m < bsj[j]+9 && m != nj[j]) a = 0.f;
                }
                att_s[(lg*4+j)*AP + colbase + s*16 + lr] = (_Float16)a;
                simacc[s][j] += a;
            }
        }
        __syncthreads();
        // PV over this wave's 64-wide k-slice
        f32x4 pv[2] = {{0.f,0.f,0.f,0.f},{0.f,0.f,0.f,0.f}};
        #pragma unroll
        for (int kc = 0; kc < 2; ++kc) {
            const int kb = colbase + kc*32;
            const half8 aA = *(const half8*)&att_s[lr*AP + kb + lg*8];
            #pragma unroll
            for (int db = 0; db < 2; ++db) {
                const half8 bV = *(const half8*)(Vth + ((size_t)(h*D + db*16 + lr))*NP + m0 + kb + lg*8);
                pv[db] = MFMA16(aA, bV, pv[db]);
            }
        }
        #pragma unroll
        for (int db = 0; db < 2; ++db)
            #pragma unroll
            for (int j = 0; j < 4; ++j)
                pvred[w][db][lg*4+j][lr] = pv[db][j];
        __syncthreads();
        // 4-way reduce + XP write (and this doubles as the pre-next-head guard region)
        for (int e = t; e < 512; e += 256) {
            const int db = e >> 8, r = (e >> 4) & 15, d0 = e & 15;
            const float sum = pvred[0][db][r][d0] + pvred[1][db][r][d0]
                            + pvred[2][db][r][d0] + pvred[3][db][r][d0];
            XP[((size_t)(mc*H + h)*N + n0 + r)*D + db*16 + d0] = sum;
        }
        __syncthreads();
    }
    // SIM direct write (register-accumulated over heads)
    #pragma unroll
    for (int s = 0; s < 4; ++s) {
        if (!mOk[s]) continue;
        #pragma unroll
        for (int j = 0; j < 4; ++j)
            SIM[(size_t)nj[j]*N + mI[s]] = simacc[s][j] * 0.125f;
    }
}

// ================= K5: reduce PV partials -> x_cat =================
__global__ __launch_bounds__(256) void reduce_kernel(
    const float* __restrict__ XP, const float* __restrict__ V, float* __restrict__ out)
{
    const int n = blockIdx.x, t = threadIdx.x;
    const int h = t >> 5, d = t & 31;
    float acc = 0.f;
    #pragma unroll
    for (int mcI = 0; mcI < 8; ++mcI)
        acc += XP[((size_t)(mcI*H + h)*N + n)*D + d];
    out[(size_t)n*512 + t] = acc;
    out[(size_t)n*512 + 256 + t] = V[((size_t)h*N + n)*D + d];
}

// ================= K6: row softmax of SIM + masked renorm =================
__global__ __launch_bounds__(256) void simfinal_kernel(
    const float* __restrict__ SIM, const unsigned char* __restrict__ Mask,
    float* __restrict__ out)
{
    __shared__ float buf[N];
    __shared__ float redA[4], redB[4];
    const int n = blockIdx.x, t = threadIdx.x;
    const float* row = SIM + (size_t)n * N;
    const unsigned char* mrow = Mask + (size_t)n * N;
    float mx = -1e30f;
    for (int i = t; i < N; i += 256) { const float v = row[i]; buf[i] = v; mx = fmaxf(mx, v); }
    #pragma unroll
    for (int off = 1; off < 64; off <<= 1) mx = fmaxf(mx, __shfl_xor(mx, off));
    const int wv = t >> 6;
    if ((t & 63) == 0) redA[wv] = mx;
    __syncthreads();
    const float M = fmaxf(fmaxf(redA[0], redA[1]), fmaxf(redA[2], redA[3]));
    float sA = 0.f, sM = 0.f;
    for (int i = t; i < N; i += 256) {
        const float e = __expf(buf[i] - M);
        buf[i] = e;
        sA += e;
        sM += mrow[i] ? e : 0.f;
    }
    #pragma unroll
    for (int off = 1; off < 64; off <<= 1) { sA += __shfl_xor(sA, off); sM += __shfl_xor(sM, off); }
    __syncthreads();
    if ((t & 63) == 0) { redA[wv] = sA; redB[wv] = sM; }
    __syncthreads();
    const float SA = redA[0] + redA[1] + redA[2] + redA[3];
    const float SMK = redB[0] + redB[1] + redB[2] + redB[3];
    const float inv = 1.f / (SMK + 1e-8f * SA);
    float* orow = out + 1024000 + (size_t)n * N;
    for (int i = t; i < N; i += 256) orow[i] = mrow[i] ? buf[i] * inv : 0.f;
}

extern "C" void kernel_launch(void* const* d_in, const int* in_sizes, int n_in,
                              void* d_out, int out_size, void* d_ws, size_t ws_size,
                              hipStream_t stream) {
    const float* x_cls     = (const float*)d_in[0];
    const float* x_reg     = (const float*)d_in[1];
    const float* cls_score = (const float*)d_in[2];
    const float* fg_score  = (const float*)d_in[3];
    const float* coord     = (const float*)d_in[4];
    const float* Wc        = (const float*)d_in[5];
    const float* Wr        = (const float*)d_in[6];

    float* ws = (float*)d_ws;
    float* V   = ws;
    float* ST  = ws + 512000;
    float* SIM = ws + 577536;
    float* XP  = ws + 4577536;
    _Float16* F16 = (_Float16*)(ws + 8673536);
    _Float16* Qch = F16;
    _Float16* Kch = F16 + 524288;
    _Float16* Qrh = F16 + 2*524288;
    _Float16* Krh = F16 + 3*524288;
    _Float16* Vnh = F16 + 4*524288;
    _Float16* Vth = F16 + 5*524288;
    unsigned char* Mask = (unsigned char*)(F16 + 6*524288);
    float* out = (float*)d_out;

    qkv_kernel<<<dim3(256, 3), 256, 0, stream>>>(x_cls, Wc, Qch, Kch, V, Vnh, Vth);
    qkv_kernel<<<dim3(256, 2), 256, 0, stream>>>(x_reg, Wr, Qrh, Krh, nullptr, nullptr, nullptr);
    stats_kernel<<<dim3(32, 8, 2), 256, 0, stream>>>(Qch, Kch, Qrh, Krh, cls_score, fg_score, ST);
    vvmask_kernel<<<dim3(8, 125), 256, 0, stream>>>(Vnh, Mask);
    attn_kernel<<<dim3(8, 125), 256, 0, stream>>>(Qch, Kch, Qrh, Krh, Vth, coord, cls_score, fg_score, ST, SIM, XP);
    reduce_kernel<<<2000, 256, 0, stream>>>(XP, V, out);
    simfinal_kernel<<<2000, 256, 0, stream>>>(SIM, Mask, out);
}

// Round 4
// 137.562 us; speedup vs baseline: 5.7605x; 1.4853x over previous
//
#include <hip/hip_runtime.h>
#include <math.h>

typedef _Float16 half8 __attribute__((ext_vector_type(8)));
typedef _Float16 half4 __attribute__((ext_vector_type(4)));
typedef float f32x4 __attribute__((ext_vector_type(4)));

constexpr int N = 2000;
constexpr int NP = 2048;   // padded row count for f16 tensors
constexpr int H = 8;
constexpr int D = 32;
constexpr float SCL = 25.0f;
constexpr float FM = 25.0f;  // fixed softmax max (scores bounded by 25)

#define MFMA16(a,b,c) __builtin_amdgcn_mfma_f32_16x16x32_f16((a),(b),(c),0,0,0)

// ---- ws layout (byte offsets) ----
// ST   f32 [2z][8h][2048]        @ 0          (131072 B)
// SIM  f32 [2000][2000]          @ 131072     (16000000 B)
// XPH  f16 [16mc][8h][2000][32]  @ 16131072   (16384000 B)
// F16  Qch,Kch,Qrh,Krh,Vnh [8][2048][32]; Vth [8][32][2048]  @ 32515072 (6x1048576 B)
// Wch  f16 [768][256]            @ 38806528   (393216 B)
// Wrh  f16 [768][256]            @ 39199744   (393216 B)
// Mask u8  [2000][2000]          @ 39592960   (4000000 B)   total ~43.6 MB

// ================= K0: convert W to f16 =================
__global__ __launch_bounds__(256) void wconv_kernel(
    const float* __restrict__ Wc, const float* __restrict__ Wr,
    _Float16* __restrict__ Wch, _Float16* __restrict__ Wrh)
{
    const int i = blockIdx.x * 256 + threadIdx.x;  // grid 768 -> 196608 exactly
    Wch[i] = (_Float16)Wc[i];
    Wrh[i] = (_Float16)Wr[i];
}

// ================= K1: QKV projection via MFMA + L2 norm =================
__global__ __launch_bounds__(256) void qkv_kernel(
    const float* __restrict__ xc, const float* __restrict__ xr,
    const _Float16* __restrict__ Wch, const _Float16* __restrict__ Wrh,
    _Float16* __restrict__ Qch, _Float16* __restrict__ Kch,
    _Float16* __restrict__ Qrh, _Float16* __restrict__ Krh,
    _Float16* __restrict__ Vnh, _Float16* __restrict__ Vth,
    float* __restrict__ out)
{
    constexpr int XS = 264;  // xs row stride (halfs), +8 pad
    __shared__ _Float16 xs[16 * XS];
    const int t = threadIdx.x;
    const int n0 = blockIdx.x * 16;
    const int by = blockIdx.y;             // 0..4: (cls q,k,v), (reg q,k)
    const int which = (by < 3) ? by : (by - 3);
    const bool isCls = by < 3;
    const float* x = isCls ? xc : xr;
    const _Float16* Wh = isCls ? Wch : Wrh;

    #pragma unroll
    for (int it = 0; it < 4; ++it) {
        const int f = t + it * 256;        // float4 index over 16x64
        const int row = f >> 6, c4 = f & 63;
        const float4 v = *(const float4*)(x + (size_t)(n0 + row) * 256 + c4 * 4);
        half4 hv; hv[0]=(_Float16)v.x; hv[1]=(_Float16)v.y; hv[2]=(_Float16)v.z; hv[3]=(_Float16)v.w;
        *(half4*)&xs[row * XS + c4 * 4] = hv;
    }
    __syncthreads();

    const int w = t >> 6, l = t & 63;
    const int lr = l & 15, lg = l >> 4;
    const int obase = which * 256 + w * 64;
    f32x4 acc[4] = {{0,0,0,0},{0,0,0,0},{0,0,0,0},{0,0,0,0}};
    for (int k0 = 0; k0 < 256; k0 += 32) {
        const half8 aX = *(const half8*)&xs[lr * XS + k0 + lg * 8];
        #pragma unroll
        for (int s = 0; s < 4; ++s) {
            const half8 bW = *(const half8*)(Wh + (size_t)(obase + s * 16 + lr) * 256 + k0 + lg * 8);
            acc[s] = MFMA16(aX, bW, acc[s]);
        }
    }
    #pragma unroll
    for (int p = 0; p < 2; ++p) {
        const int h = 2 * w + p;
        float ss[4];
        #pragma unroll
        for (int j = 0; j < 4; ++j) {
            float v = acc[2*p][j]*acc[2*p][j] + acc[2*p+1][j]*acc[2*p+1][j];
            #pragma unroll
            for (int off = 1; off < 16; off <<= 1) v += __shfl_xor(v, off);
            ss[j] = sqrtf(v) + 1e-8f;
        }
        if (which < 2) {
            _Float16* Qd = isCls ? (which == 0 ? Qch : Kch) : (which == 0 ? Qrh : Krh);
            #pragma unroll
            for (int sh = 0; sh < 2; ++sh)
                #pragma unroll
                for (int j = 0; j < 4; ++j)
                    Qd[((size_t)h*NP + n0 + lg*4 + j)*D + sh*16 + lr] = (_Float16)(acc[2*p+sh][j] / ss[j]);
        } else {
            #pragma unroll
            for (int sh = 0; sh < 2; ++sh) {
                const int d = sh * 16 + lr;
                half4 tv;
                #pragma unroll
                for (int j = 0; j < 4; ++j) {
                    const float raw = acc[2*p+sh][j];
                    Vnh[((size_t)h*NP + n0 + lg*4 + j)*D + d] = (_Float16)(raw / ss[j]);
                    out[(size_t)(n0 + lg*4 + j)*512 + 256 + h*D + d] = raw;
                    tv[j] = (_Float16)raw;
                }
                *(half4*)(Vth + ((size_t)h*D + d)*NP + n0 + lg*4) = tv;
            }
        }
    }
}

// ================= K2: softmax denom (fixed max M=25) via MFMA =================
__global__ __launch_bounds__(512) void stats_kernel(
    const _Float16* __restrict__ Qch, const _Float16* __restrict__ Kch,
    const _Float16* __restrict__ Qrh, const _Float16* __restrict__ Krh,
    const float* __restrict__ clsScore, const float* __restrict__ fgScore,
    float* __restrict__ ST)
{
    __shared__ float Ssh[4][2][16];
    const int t = threadIdx.x;
    const int w = t >> 6, l = t & 63;
    const int nsub = w >> 1, mhalf = w & 1;
    const int n0 = blockIdx.x * 64 + nsub * 16;
    const int h = blockIdx.y, z = blockIdx.z;
    const _Float16* Q = z ? Qrh : Qch;
    const _Float16* K = z ? Krh : Kch;
    const float* score = z ? fgScore : clsScore;
    const int lr = l & 15, lg = l >> 4;
    const half8 aQ = *(const half8*)(Q + ((size_t)h*NP + n0 + lr)*D + lg*8);
    float S[4] = {0.f, 0.f, 0.f, 0.f};
    const int msBeg = mhalf ? 63 : 0;
    const int msEnd = mhalf ? 125 : 63;
    for (int ms = msBeg; ms < msEnd; ++ms) {
        const int m = ms * 16 + lr;
        const half8 bK = *(const half8*)(K + ((size_t)h*NP + m)*D + lg*8);
        f32x4 z4 = {0.f, 0.f, 0.f, 0.f};
        const f32x4 c = MFMA16(aQ, bK, z4);
        const float sm = SCL * score[m];
        #pragma unroll
        for (int j = 0; j < 4; ++j) S[j] += __expf(fmaf(c[j], sm, -FM));
    }
    #pragma unroll
    for (int j = 0; j < 4; ++j) {
        #pragma unroll
        for (int off = 1; off < 16; off <<= 1) S[j] += __shfl_xor(S[j], off);
    }
    if (lr == 0) {
        #pragma unroll
        for (int j = 0; j < 4; ++j) Ssh[nsub][mhalf][lg*4 + j] = S[j];
    }
    __syncthreads();
    if (t < 64) {
        const int ns = t >> 4, rl = t & 15;
        ST[((size_t)z*H + h)*NP + blockIdx.x*64 + ns*16 + rl] = Ssh[ns][0][rl] + Ssh[ns][1][rl];
    }
}

// ================= K3: mean-over-h of Vn.Vn^T -> u8 mask (MFMA) =================
__global__ __launch_bounds__(256) void vvmask_kernel(
    const _Float16* __restrict__ Vnh, unsigned char* __restrict__ Mask)
{
    const int t = threadIdx.x;
    const int w = t >> 6, l = t & 63;
    const int n0 = blockIdx.y * 16;
    const int m00 = blockIdx.x * 256 + w * 64;
    const int lr = l & 15, lg = l >> 4;
    half8 aV[8];
    #pragma unroll
    for (int h = 0; h < 8; ++h)
        aV[h] = *(const half8*)(Vnh + ((size_t)(h*NP + n0 + lr))*D + lg*8);
    for (int s = 0; s < 4; ++s) {
        const int mb = m00 + s*16;
        f32x4 acc = {0.f, 0.f, 0.f, 0.f};
        #pragma unroll
        for (int h = 0; h < 8; ++h) {
            const half8 bV = *(const half8*)(Vnh + ((size_t)(h*NP + mb + lr))*D + lg*8);
            acc = MFMA16(aV[h], bV, acc);
        }
        const int m = mb + lr;
        if (m < N) {
            #pragma unroll
            for (int j = 0; j < 4; ++j) {
                const int n = n0 + lg*4 + j;
                Mask[(size_t)n*N + m] = (acc[j]*0.125f > 0.75f) ? (unsigned char)1 : (unsigned char)0;
            }
        }
    }
}

// ================= K4: fused attention, mc=16, fixed-max, f16 pvred/XP =================
__global__ __launch_bounds__(256) void attn_kernel(
    const _Float16* __restrict__ Qch, const _Float16* __restrict__ Kch,
    const _Float16* __restrict__ Qrh, const _Float16* __restrict__ Krh,
    const _Float16* __restrict__ Vth, const float* __restrict__ coord,
    const float* __restrict__ clsScore, const float* __restrict__ fgScore,
    const float* __restrict__ ST,
    float* __restrict__ SIM, _Float16* __restrict__ XPH)
{
    constexpr int AP = 136;  // att_s col stride (halfs), 128 + 8 pad
    __shared__ _Float16 att_s[16 * AP];
    __shared__ _Float16 pvred[4][2][16][18];
    __shared__ float st_s[2][H][16];

    const int t = threadIdx.x;
    const int w = t >> 6, l = t & 63;
    const int mc = blockIdx.x;
    const int m0 = mc * 128;
    const int n0 = blockIdx.y * 16;
    const int lr = l & 15, lg = l >> 4;
    const int colbase = w * 32;

    {   // 2*8*16 = 256 entries, one per thread
        const int z = t >> 7, h = (t >> 4) & 7, r = t & 15;
        st_s[z][h][r] = 1.f / ST[((size_t)z*H + h)*NP + n0 + r];
    }
    int mI[2]; bool mOk[2]; float sC[2], sF[2];
    #pragma unroll
    for (int s = 0; s < 2; ++s) {
        mI[s] = m0 + colbase + s*16 + lr;
        mOk[s] = mI[s] < N;
        sC[s] = mOk[s] ? SCL * clsScore[mI[s]] : 0.f;
        sF[s] = mOk[s] ? SCL * fgScore[mI[s]] : 0.f;
    }
    int nj[4], bsj[4];
    #pragma unroll
    for (int j = 0; j < 4; ++j) { nj[j] = n0 + lg*4 + j; bsj[j] = (nj[j]/10)*10; }
    float simacc[2][4] = {{0,0,0,0},{0,0,0,0}};
    __syncthreads();

    for (int h = 0; h < H; ++h) {
        float co[2][4];
        #pragma unroll
        for (int s = 0; s < 2; ++s)
            #pragma unroll
            for (int j = 0; j < 4; ++j)
                co[s][j] = mOk[s] ? coord[((size_t)h*N + nj[j])*N + mI[s]] : 0.f;

        const half8 aQc = *(const half8*)(Qch + ((size_t)h*NP + n0 + lr)*D + lg*8);
        const half8 aQr = *(const half8*)(Qrh + ((size_t)h*NP + n0 + lr)*D + lg*8);
        float iC[4], iR[4];
        #pragma unroll
        for (int j = 0; j < 4; ++j) { iC[j] = st_s[0][h][lg*4+j]; iR[j] = st_s[1][h][lg*4+j]; }

        #pragma unroll
        for (int s = 0; s < 2; ++s) {
            const int mb = m0 + colbase + s*16;
            const half8 bKc = *(const half8*)(Kch + ((size_t)h*NP + mb + lr)*D + lg*8);
            const half8 bKr = *(const half8*)(Krh + ((size_t)h*NP + mb + lr)*D + lg*8);
            f32x4 z4 = {0.f, 0.f, 0.f, 0.f};
            const f32x4 cc = MFMA16(aQc, bKc, z4);
            const f32x4 cr = MFMA16(aQr, bKr, z4);
            #pragma unroll
            for (int j = 0; j < 4; ++j) {
                float a = 0.f;
                if (mOk[s]) {
                    const float eC = __expf(fmaf(cc[j], sC[s], -FM)) * iC[j];
                    const float eR = __expf(fmaf(cr[j], sF[s], -FM)) * iR[j];
                    a = (eC + eR) * 0.5f * co[s][j];
                    if (mI[s] >= bsj[j] && mI[s] < bsj[j]+9 && mI[s] != nj[j]) a = 0.f;
                }
                att_s[(lg*4+j)*AP + colbase + s*16 + lr] = (_Float16)a;
                simacc[s][j] += a;
            }
        }
        // PV over this wave's OWN 32-col k-slice: no barrier needed (same-wave LDS RAW)
        f32x4 pv0 = {0.f,0.f,0.f,0.f}, pv1 = {0.f,0.f,0.f,0.f};
        {
            const half8 aA  = *(const half8*)&att_s[lr*AP + colbase + lg*8];
            const half8 bV0 = *(const half8*)(Vth + ((size_t)h*D + lr)*NP + m0 + colbase + lg*8);
            const half8 bV1 = *(const half8*)(Vth + ((size_t)h*D + 16 + lr)*NP + m0 + colbase + lg*8);
            pv0 = MFMA16(aA, bV0, pv0);
            pv1 = MFMA16(aA, bV1, pv1);
        }
        #pragma unroll
        for (int j = 0; j < 4; ++j) {
            pvred[w][0][lg*4+j][lr] = (_Float16)pv0[j];
            pvred[w][1][lg*4+j][lr] = (_Float16)pv1[j];
        }
        __syncthreads();
        #pragma unroll
        for (int e = t; e < 512; e += 256) {
            const int db = e >> 8, r = (e >> 4) & 15, d0 = e & 15;
            const float sum = (float)pvred[0][db][r][d0] + (float)pvred[1][db][r][d0]
                            + (float)pvred[2][db][r][d0] + (float)pvred[3][db][r][d0];
            XPH[(((size_t)mc*H + h)*N + n0 + r)*D + db*16 + d0] = (_Float16)sum;
        }
        __syncthreads();
    }
    #pragma unroll
    for (int s = 0; s < 2; ++s) {
        if (!mOk[s]) continue;
        #pragma unroll
        for (int j = 0; j < 4; ++j)
            SIM[(size_t)nj[j]*N + mI[s]] = simacc[s][j] * 0.125f;
    }
}

// ================= K5: reduce XP partials -> x =================
__global__ __launch_bounds__(256) void reduce_kernel(
    const _Float16* __restrict__ XPH, float* __restrict__ out)
{
    const int n = blockIdx.x, t = threadIdx.x;
    const int h = t >> 5, d = t & 31;
    float acc = 0.f;
    #pragma unroll
    for (int mcI = 0; mcI < 16; ++mcI)
        acc += (float)XPH[(((size_t)mcI*H + h)*N + n)*D + d];
    out[(size_t)n*512 + t] = acc;
}

// ================= K6: row softmax of SIM + masked renorm (float4) =================
__global__ __launch_bounds__(256) void simfinal_kernel(
    const float* __restrict__ SIM, const unsigned char* __restrict__ Mask,
    float* __restrict__ out)
{
    __shared__ float4 buf[500];
    __shared__ float redA[4], redB[4];
    const int n = blockIdx.x, t = threadIdx.x;
    const float4* row4 = (const float4*)(SIM + (size_t)n*N);
    const uchar4* mrow4 = (const uchar4*)(Mask + (size_t)n*N);
    float mx = -1e30f;
    for (int i = t; i < 500; i += 256) {
        const float4 v = row4[i];
        buf[i] = v;
        mx = fmaxf(mx, fmaxf(fmaxf(v.x, v.y), fmaxf(v.z, v.w)));
    }
    #pragma unroll
    for (int off = 1; off < 64; off <<= 1) mx = fmaxf(mx, __shfl_xor(mx, off));
    const int wv = t >> 6;
    if ((t & 63) == 0) redA[wv] = mx;
    __syncthreads();
    const float M = fmaxf(fmaxf(redA[0], redA[1]), fmaxf(redA[2], redA[3]));
    float sA = 0.f, sM = 0.f;
    for (int i = t; i < 500; i += 256) {
        float4 v = buf[i];
        const uchar4 mk = mrow4[i];
        v.x = __expf(v.x - M); v.y = __expf(v.y - M);
        v.z = __expf(v.z - M); v.w = __expf(v.w - M);
        buf[i] = v;
        sA += v.x + v.y + v.z + v.w;
        sM += (mk.x ? v.x : 0.f) + (mk.y ? v.y : 0.f) + (mk.z ? v.z : 0.f) + (mk.w ? v.w : 0.f);
    }
    #pragma unroll
    for (int off = 1; off < 64; off <<= 1) { sA += __shfl_xor(sA, off); sM += __shfl_xor(sM, off); }
    __syncthreads();
    if ((t & 63) == 0) { redA[wv] = sA; redB[wv] = sM; }
    __syncthreads();
    const float SA = redA[0] + redA[1] + redA[2] + redA[3];
    const float SMK = redB[0] + redB[1] + redB[2] + redB[3];
    const float inv = 1.f / (SMK + 1e-8f * SA);
    float4* orow = (float4*)(out + 1024000 + (size_t)n*N);
    for (int i = t; i < 500; i += 256) {
        const float4 v = buf[i];
        const uchar4 mk = mrow4[i];
        orow[i] = make_float4(mk.x ? v.x * inv : 0.f, mk.y ? v.y * inv : 0.f,
                              mk.z ? v.z * inv : 0.f, mk.w ? v.w * inv : 0.f);
    }
}

extern "C" void kernel_launch(void* const* d_in, const int* in_sizes, int n_in,
                              void* d_out, int out_size, void* d_ws, size_t ws_size,
                              hipStream_t stream) {
    const float* x_cls     = (const float*)d_in[0];
    const float* x_reg     = (const float*)d_in[1];
    const float* cls_score = (const float*)d_in[2];
    const float* fg_score  = (const float*)d_in[3];
    const float* coord     = (const float*)d_in[4];
    const float* Wc        = (const float*)d_in[5];
    const float* Wr        = (const float*)d_in[6];

    char* base = (char*)d_ws;
    float* ST       = (float*)base;
    float* SIM      = (float*)(base + 131072);
    _Float16* XPH   = (_Float16*)(base + 16131072);
    _Float16* Qch   = (_Float16*)(base + 32515072);
    _Float16* Kch   = Qch + 524288;
    _Float16* Qrh   = Qch + 2*524288;
    _Float16* Krh   = Qch + 3*524288;
    _Float16* Vnh   = Qch + 4*524288;
    _Float16* Vth   = Qch + 5*524288;
    _Float16* Wch   = (_Float16*)(base + 38806528);
    _Float16* Wrh   = (_Float16*)(base + 39199744);
    unsigned char* Mask = (unsigned char*)(base + 39592960);
    float* out = (float*)d_out;

    hipMemsetAsync(Qch, 0, 6*1048576, stream);   // zero f16 tensors (covers pad rows/cols)
    wconv_kernel<<<768, 256, 0, stream>>>(Wc, Wr, Wch, Wrh);
    qkv_kernel<<<dim3(125, 5), 256, 0, stream>>>(x_cls, x_reg, Wch, Wrh,
                                                 Qch, Kch, Qrh, Krh, Vnh, Vth, out);
    stats_kernel<<<dim3(32, 8, 2), 512, 0, stream>>>(Qch, Kch, Qrh, Krh, cls_score, fg_score, ST);
    vvmask_kernel<<<dim3(8, 125), 256, 0, stream>>>(Vnh, Mask);
    attn_kernel<<<dim3(16, 125), 256, 0, stream>>>(Qch, Kch, Qrh, Krh, Vth, coord,
                                                   cls_score, fg_score, ST, SIM, XPH);
    reduce_kernel<<<2000, 256, 0, stream>>>(XPH, out);
    simfinal_kernel<<<2000, 256, 0, stream>>>(SIM, Mask, out);
}